// Round 1
// baseline (319.574 us; speedup 1.0000x reference)
//
#include <hip/hip_runtime.h>

// B=4, N=8, C=256, H=64, W=64, D=512 (single query per batch).
// Algebraic collapse (see R1): c is read exactly once; K and V never formed.
//   gqk[b,c]  = g[c] * D^-0.5 * (Wkv_upper^T (Wq q_b))[c]
//   dots[n]   = inv_rms[n] * <cp[n,:], gqk[b,:]>   (per pixel)
//   t[c]      = sum_n softmax_n * inv_rms[n] * cp[n,c]
//   out       = Wovg @ t + bo,  Wovg = Wo @ Wkv_lower * diag(g)  (bf16 MFMA)
//
// R3: attn re-tiled 256->512 threads/block (8 waves). Per-thread channel
// state halves (rg/vals/t_reg 16 each, ~80 VGPR) -> __launch_bounds__(512,4)
// -> 4 waves/SIMD (16 waves/CU, whole grid resident) vs the old 2/SIMD.
// Same 128B-aligned coalescing (hf split), one barrier per token, phase-3
// MFMA identical modulo wave->row-tile mapping (Av layout unchanged).

typedef __attribute__((ext_vector_type(8))) short short8;
typedef __attribute__((ext_vector_type(4))) float floatx4;

static __device__ __forceinline__ short f2bf(float f) {
  unsigned u = __float_as_uint(f);
  u += 0x7fffu + ((u >> 16) & 1u);   // round-to-nearest-even
  return (short)(u >> 16);
}

// ws: [0,131072) WovgB bf16, A-fragment-linear: element (i,c) at short index
//     ((((i>>4)*8 + (c>>5))*4 + ((c>>3)&3))*16 + (i&15))*8 + (c&7)
//     [131072,135168) gqk f32 [4][256]
__global__ __launch_bounds__(256) void pre_kernel(
    const float* __restrict__ q, const float* __restrict__ g,
    const float* __restrict__ Wq, const float* __restrict__ Wkv,
    const float* __restrict__ Wo, unsigned char* __restrict__ ws) {
  short* WovgB = (short*)ws;
  float* gqk = (float*)(ws + 131072);
  const int blk = blockIdx.x, tid = threadIdx.x;
  if (blk < 256) {
    const int i = blk, c = tid;
    float s = 0.f;
    #pragma unroll 16
    for (int d = 0; d < 512; ++d)
      s = fmaf(Wo[i * 512 + d], Wkv[(512 + d) * 256 + c], s);
    const int it = i >> 4, m = i & 15;
    const int sg = c >> 5, q2 = (c >> 3) & 3, jj = c & 7;
    WovgB[((((it * 8 + sg) * 4 + q2) * 16) + m) * 8 + jj] = f2bf(s * g[c]);
  } else {
    const int b = blk - 256;
    __shared__ float qps[512];
    for (int d = tid; d < 512; d += 256) {
      float s = 0.f;
      #pragma unroll 16
      for (int cc = 0; cc < 256; ++cc)
        s = fmaf(Wq[d * 256 + cc], q[b * 256 + cc], s);
      qps[d] = s;
    }
    __syncthreads();
    const int c = tid;
    float s = 0.f;
    #pragma unroll 16
    for (int d = 0; d < 512; ++d)
      s = fmaf(Wkv[d * 256 + c], qps[d], s);
    gqk[b * 256 + c] = s * g[c] * 0.044194173824159216f;  // 512^-0.5
  }
}

// Block = (b, h, half-row): 32 px, 512 threads = 8 waves.
// Wave w owns ch [w*32, w*32+32); lane = cs*32+px, cs in {0,1} owns
// ch [w*32+cs*16, w*32+cs*16+16). 512 blocks -> 2 blocks/CU, 16 waves/CU.
__global__ __launch_bounds__(512, 4) void attn_kernel(
    const float* __restrict__ cin, const float* __restrict__ bo,
    const unsigned char* __restrict__ ws, float* __restrict__ out) {
  const short8* Av = (const short8*)ws;
  const float* gqk = (const float*)(ws + 131072);
  const int blk = blockIdx.x;                 // 512 blocks
  const int b = blk >> 7, h = (blk >> 1) & 63, hf = blk & 1;
  const int tid = threadIdx.x;
  const int lane = tid & 63, w = tid >> 6;    // w in 0..7
  const int px = lane & 31, cs = lane >> 5;   // cs in 0..1

  __shared__ short tB[8][2][64][8];           // 16 KB, B-fragment-linear
  __shared__ float redS[2][8][32], redD[2][8][32];  // 4 KB

  float rg[16];
  #pragma unroll
  for (int j = 0; j < 16; ++j) rg[j] = gqk[b * 256 + w * 32 + cs * 16 + j];

  float t_reg[16];
  #pragma unroll
  for (int j = 0; j < 16; ++j) t_reg[j] = 0.f;
  float mM = -1e30f, zZ = 0.f;

  const float* cb = cin + ((size_t)(b * 8) * 256 + w * 32 + cs * 16) * 4096
                        + h * 64 + hf * 32 + px;
  for (int n = 0; n < 8; ++n) {
    const float* cp = cb + (size_t)n * 256 * 4096;
    float vals[16];
    #pragma unroll
    for (int j = 0; j < 16; ++j) vals[j] = cp[(size_t)j * 4096];
    float ssq = 0.f, dt = 0.f;
    #pragma unroll
    for (int j = 0; j < 16; ++j) {
      ssq = fmaf(vals[j], vals[j], ssq);
      dt = fmaf(vals[j], rg[j], dt);
    }
    ssq += __shfl_xor(ssq, 32);               // combine the wave's 2 cs halves
    dt  += __shfl_xor(dt, 32);
    if (cs == 0) { redS[n & 1][w][px] = ssq; redD[n & 1][w][px] = dt; }
    __syncthreads();                          // the only barrier per token
    float S = 0.f, Dt = 0.f;
    #pragma unroll
    for (int ww = 0; ww < 8; ++ww) { S += redS[n & 1][ww][px]; Dt += redD[n & 1][ww][px]; }
    const float invr = rsqrtf(S * (1.f / 256.f) + 1e-6f);
    const float d = Dt * invr;
    const float mn = fmaxf(mM, d);
    const float al = __expf(mM - mn);         // 0 on first token
    const float e = __expf(d - mn);
    zZ = zZ * al + e;
    mM = mn;
    const float wn = e * invr;
    #pragma unroll
    for (int j = 0; j < 16; ++j) t_reg[j] = fmaf(wn, vals[j], t_reg[j] * al);
  }

  // write normalized t (bf16) in B-fragment order:
  // reader lane L=(q*16+m) of (s,nt) wants ch=s*32+q*8+jj, px=nt*16+m.
  // writer ch = w*32 + cs*16 + g*8 + jj  ->  s = w, q = cs*2+g.
  {
    const float invZ = 1.f / zZ;
    const int nt = px >> 4, mm = px & 15;
    #pragma unroll
    for (int g = 0; g < 2; ++g) {
      short8 pk;
      #pragma unroll
      for (int jj = 0; jj < 8; ++jj) pk[jj] = f2bf(t_reg[g * 8 + jj] * invZ);
      *(short8*)(&tB[w][nt][(cs * 2 + g) * 16 + mm][0]) = pk;
    }
  }
  __syncthreads();

  // phase 3: out[256 i][32 px] = Wovg(bf16) @ t(bf16); wave ig -> 32 i-rows
  const int ig = __builtin_amdgcn_readfirstlane(w);
  const int qf = lane >> 4, m = lane & 15;
  const short8* Bv = (const short8*)tB;
  floatx4 acc[2][2];
  #pragma unroll
  for (int mt = 0; mt < 2; ++mt)
    #pragma unroll
    for (int nt = 0; nt < 2; ++nt) acc[mt][nt] = (floatx4){0.f, 0.f, 0.f, 0.f};
  #pragma unroll
  for (int s = 0; s < 8; ++s) {
    short8 a[2];
    #pragma unroll
    for (int mt = 0; mt < 2; ++mt)            // coalesced: 16 B/lane, 1 KB/wave
      a[mt] = Av[(((ig * 2 + mt) * 8 + s) * 4 + qf) * 16 + m];
    #pragma unroll
    for (int nt = 0; nt < 2; ++nt) {
      const short8 bf = Bv[(s * 2 + nt) * 64 + lane];
      #pragma unroll
      for (int mt = 0; mt < 2; ++mt)
        acc[mt][nt] = __builtin_amdgcn_mfma_f32_16x16x32_bf16(a[mt], bf, acc[mt][nt], 0, 0, 0);
    }
  }
  // epilogue: D layout col=lane&15(px), row=qf*4+r(i)
  float* ob = out + (size_t)b * 256 * 4096 + h * 64 + hf * 32;
  #pragma unroll
  for (int mt = 0; mt < 2; ++mt) {
    float bov[4];
    #pragma unroll
    for (int r = 0; r < 4; ++r) bov[r] = bo[ig * 32 + mt * 16 + qf * 4 + r];
    #pragma unroll
    for (int nt = 0; nt < 2; ++nt)
      #pragma unroll
      for (int r = 0; r < 4; ++r) {
        const int i = ig * 32 + mt * 16 + qf * 4 + r;
        ob[(size_t)i * 4096 + nt * 16 + m] = acc[mt][nt][r] + bov[r];
      }
  }
}

extern "C" void kernel_launch(void* const* d_in, const int* in_sizes, int n_in,
                              void* d_out, int out_size, void* d_ws, size_t ws_size,
                              hipStream_t stream) {
  const float* q   = (const float*)d_in[0];
  const float* c   = (const float*)d_in[1];
  const float* g   = (const float*)d_in[2];
  const float* Wq  = (const float*)d_in[3];
  const float* Wkv = (const float*)d_in[4];
  const float* Wo  = (const float*)d_in[5];
  const float* bo  = (const float*)d_in[6];
  float* out = (float*)d_out;
  unsigned char* ws = (unsigned char*)d_ws;   // needs 135168 bytes
  pre_kernel<<<260, 256, 0, stream>>>(q, g, Wq, Wkv, Wo, ws);
  attn_kernel<<<512, 512, 0, stream>>>(c, bo, ws, out);
}

// Round 2
// 275.968 us; speedup vs baseline: 1.1580x; 1.1580x over previous
//
#include <hip/hip_runtime.h>

// B=4, N=8, C=256, H=64, W=64, D=512 (single query per batch).
// Algebraic collapse: c is the only large tensor; K and V never formed.
//   gqk[b,c]  = g[c] * D^-0.5 * (Wkv_upper^T (Wq q_b))[c]
//   d[n,px]   = invr[n,px] * <c[b,n,:,px], gqk[b,:]>
//   t[c,px]   = sum_n softmax_n(d) * invr * c[b,n,c,px]
//   out       = Wovg @ t + bo,  Wovg = Wo @ Wkv_lower * diag(g)  (bf16 MFMA)
//
// R4: the single-pass kernel was DRAM row-activation-bound (128 B per 16 KB
// stride -> 2.3 TB/s ceiling; R3's spills doubled traffic on top). Split into
// streaming passes with 1-2 KB contiguous spans per channel plane:
//   stats_kernel: c read #1 (contiguous), emit (d, invr) per (b,px,n)  [1 MB]
//   wsum_kernel : c read #2 (contiguous), exact softmax from stats,
//                 t accumulated in regs (16 ch/thread, ~40 VGPR -> no spill
//                 even under the 64-reg occupancy squeeze that killed R3),
//                 write t as bf16 B-fragments [8.4 MB]
//   gemm_kernel : out = Wovg @ t + bo via 16x16x32 bf16 MFMA.
// ws: [0,131072)        WovgB bf16, A-fragment-linear:
//                       (i,c) -> ((((i>>4)*8+(c>>5))*4+((c>>3)&3))*16+(i&15))*8+(c&7)
//     [131072,135168)   gqk f32 [4][256]
//     [135168,1183744)  stats float2 [4][4096 px][8 n] = (d, invr)
//     [1183744,9572352) tfrag bf16: (b,P=px>>4,s,q,m=px&15,jj) ->
//                       short idx ((((b*256+P)*8+s)*4+q)*16+m)*8+jj

typedef __attribute__((ext_vector_type(8))) short short8;
typedef __attribute__((ext_vector_type(4))) float floatx4;

static __device__ __forceinline__ short f2bf(float f) {
  unsigned u = __float_as_uint(f);
  u += 0x7fffu + ((u >> 16) & 1u);   // round-to-nearest-even
  return (short)(u >> 16);
}

// blocks 0..63: Wovg rows 4i..4i+3 (each block reads Wkv_lower once: 512 KB L2)
// blocks 64..67: gqk for batch b
__global__ __launch_bounds__(256) void pre_kernel(
    const float* __restrict__ q, const float* __restrict__ g,
    const float* __restrict__ Wq, const float* __restrict__ Wkv,
    const float* __restrict__ Wo, unsigned char* __restrict__ ws) {
  short* WovgB = (short*)ws;
  float* gqk = (float*)(ws + 131072);
  const int blk = blockIdx.x, tid = threadIdx.x;
  if (blk < 64) {
    const int i0 = blk * 4, c = tid;
    float s0 = 0.f, s1 = 0.f, s2 = 0.f, s3 = 0.f;
    #pragma unroll 8
    for (int d = 0; d < 512; ++d) {
      const float wv = Wkv[(512 + d) * 256 + c];   // vector load
      s0 = fmaf(Wo[(i0 + 0) * 512 + d], wv, s0);   // Wo: uniform -> s_load
      s1 = fmaf(Wo[(i0 + 1) * 512 + d], wv, s1);
      s2 = fmaf(Wo[(i0 + 2) * 512 + d], wv, s2);
      s3 = fmaf(Wo[(i0 + 3) * 512 + d], wv, s3);
    }
    const float gc = g[c];
    const int sg = c >> 5, q2 = (c >> 3) & 3, jj = c & 7;
    const float sv[4] = {s0, s1, s2, s3};
    #pragma unroll
    for (int ii = 0; ii < 4; ++ii) {
      const int i = i0 + ii, it = i >> 4, m = i & 15;
      WovgB[((((it * 8 + sg) * 4 + q2) * 16) + m) * 8 + jj] = f2bf(sv[ii] * gc);
    }
  } else if (blk < 68) {
    const int b = blk - 64;
    __shared__ float qps[512];
    for (int d = tid; d < 512; d += 256) {
      float s = 0.f;
      #pragma unroll 16
      for (int cc = 0; cc < 256; ++cc)
        s = fmaf(Wq[d * 256 + cc], q[b * 256 + cc], s);
      qps[d] = s;
    }
    __syncthreads();
    const int c = tid;
    float s = 0.f;
    #pragma unroll 16
    for (int d = 0; d < 512; ++d)
      s = fmaf(Wkv[d * 256 + c], qps[d], s);
    gqk[b * 256 + c] = s * g[c] * 0.044194173824159216f;  // 512^-0.5
  }
}

// Pass 1: per-(px,n) stats. Block = (b, n, 512-px tile): reads 2 KB contiguous
// per channel plane (DRAM page-friendly). 256 blocks x 512 thr, ~20 VGPR.
__global__ __launch_bounds__(512) void stats_kernel(
    const float* __restrict__ cin, unsigned char* __restrict__ ws) {
  const float* gqk = (const float*)(ws + 131072);
  float2* stats = (float2*)(ws + 135168);
  const int blk = blockIdx.x, tid = threadIdx.x;
  const int b = blk >> 6, n = (blk >> 3) & 7, pt = blk & 7;
  const int px = pt * 512 + tid;
  const float* cp = cin + (size_t)(b * 8 + n) * 256 * 4096 + px;
  float ssq = 0.f, dt = 0.f;
  #pragma unroll 16
  for (int ch = 0; ch < 256; ++ch) {
    const float v = cp[(size_t)ch * 4096];
    const float gq = gqk[b * 256 + ch];            // uniform -> s_load
    ssq = fmaf(v, v, ssq);
    dt = fmaf(v, gq, dt);
  }
  const float invr = rsqrtf(ssq * (1.f / 256.f) + 1e-6f);
  stats[((size_t)(b * 4096 + px)) * 8 + n] = make_float2(dt * invr, invr);
}

// Pass 2: t accumulation. Block = (b, 16-ch group, 256-px tile): 1 KB spans.
// 1024 blocks x 256 thr -> 4 blocks/CU, 16 waves/CU. Per thread: t[16]+wn[8]
// (~40 VGPR: no spill even if the allocator squeezes to 64 regs).
__global__ __launch_bounds__(256) void wsum_kernel(
    const float* __restrict__ cin, unsigned char* __restrict__ ws) {
  const float2* stats = (const float2*)(ws + 135168);
  short8* tfrag = (short8*)(ws + 1183744);
  const int blk = blockIdx.x, tid = threadIdx.x;
  const int b = blk >> 8, cg = (blk >> 4) & 15, pt = blk & 15;
  const int px = pt * 256 + tid;

  // exact softmax weights from stats (all 8 dots known -> no online rescale)
  float d[8], ir[8];
  const float4* sp = (const float4*)(stats + ((size_t)(b * 4096 + px)) * 8);
  #pragma unroll
  for (int k = 0; k < 4; ++k) {
    const float4 v = sp[k];
    d[2 * k] = v.x; ir[2 * k] = v.y; d[2 * k + 1] = v.z; ir[2 * k + 1] = v.w;
  }
  float mx = d[0];
  #pragma unroll
  for (int n = 1; n < 8; ++n) mx = fmaxf(mx, d[n]);
  float wn[8], Z = 0.f;
  #pragma unroll
  for (int n = 0; n < 8; ++n) { wn[n] = __expf(d[n] - mx); Z += wn[n]; }
  const float iZ = 1.f / Z;
  #pragma unroll
  for (int n = 0; n < 8; ++n) wn[n] *= iZ * ir[n];

  float t[16];
  #pragma unroll
  for (int j = 0; j < 16; ++j) t[j] = 0.f;
  const float* cb = cin + ((size_t)(b * 8) * 256 + cg * 16) * 4096 + px;
  #pragma unroll
  for (int n = 0; n < 8; ++n) {
    const float* cp = cb + (size_t)n * 256 * 4096;
    #pragma unroll
    for (int j = 0; j < 16; ++j)
      t[j] = fmaf(wn[n], cp[(size_t)j * 4096], t[j]);
  }

  // write B-fragments: ch = cg*16 + qh*8 + jj -> s = cg>>1, q = (cg&1)*2+qh
  const int P = px >> 4, m = px & 15, s = cg >> 1;
  #pragma unroll
  for (int qh = 0; qh < 2; ++qh) {
    const int qq = (cg & 1) * 2 + qh;
    short8 pk;
    #pragma unroll
    for (int jj = 0; jj < 8; ++jj) pk[jj] = f2bf(t[qh * 8 + jj]);
    tfrag[(((b * 256 + P) * 8 + s) * 4 + qq) * 16 + m] = pk;
  }
}

// Pass 3: out[256 i][256 px] per block = Wovg(bf16) @ t(bf16) + bo.
// Block = (b, ig: 64 i-rows, pxg: 256 px). 256 blocks x 256 thr (4 waves).
__global__ __launch_bounds__(256, 2) void gemm_kernel(
    const float* __restrict__ bo, const unsigned char* __restrict__ ws,
    float* __restrict__ out) {
  const short8* Av = (const short8*)ws;
  const short8* Tv = (const short8*)(ws + 1183744);
  __shared__ short8 tBs[1024];   // 16 KB: t[32 ch][256 px] for current s
  const int blk = blockIdx.x, tid = threadIdx.x;
  const int b = blk >> 6, ig = (blk >> 4) & 3, pxg = blk & 15;
  const int lane = tid & 63, w = tid >> 6;
  const int it = ig * 4 + w;                  // wave -> 16 i-rows
  const int qf = lane >> 4, m = lane & 15;
  floatx4 acc[16];
  #pragma unroll
  for (int nt = 0; nt < 16; ++nt) acc[nt] = (floatx4){0.f, 0.f, 0.f, 0.f};
  #pragma unroll
  for (int s = 0; s < 8; ++s) {
    if (s) __syncthreads();                   // protect tBs reuse
    #pragma unroll
    for (int k = 0; k < 4; ++k) {             // stage 16 KB, coalesced 16 B/lane
      const int idx = tid + k * 256;
      const int nt = idx >> 6, r = idx & 63;
      tBs[idx] = Tv[(size_t)((b * 256 + pxg * 16 + nt) * 8 + s) * 64 + r];
    }
    __syncthreads();
    const short8 a = Av[((it * 8 + s) * 4 + qf) * 16 + m];
    #pragma unroll
    for (int nt = 0; nt < 16; ++nt)
      acc[nt] = __builtin_amdgcn_mfma_f32_16x16x32_bf16(a, tBs[nt * 64 + lane], acc[nt], 0, 0, 0);
  }
  // D layout: col = m (px), row = qf*4 + r (i)
  float* ob = out + (size_t)(b * 256) * 4096 + pxg * 256;
  #pragma unroll
  for (int nt = 0; nt < 16; ++nt)
    #pragma unroll
    for (int r = 0; r < 4; ++r) {
      const int i = it * 16 + qf * 4 + r;
      ob[(size_t)i * 4096 + nt * 16 + m] = acc[nt][r] + bo[i];
    }
}

extern "C" void kernel_launch(void* const* d_in, const int* in_sizes, int n_in,
                              void* d_out, int out_size, void* d_ws, size_t ws_size,
                              hipStream_t stream) {
  const float* q   = (const float*)d_in[0];
  const float* c   = (const float*)d_in[1];
  const float* g   = (const float*)d_in[2];
  const float* Wq  = (const float*)d_in[3];
  const float* Wkv = (const float*)d_in[4];
  const float* Wo  = (const float*)d_in[5];
  const float* bo  = (const float*)d_in[6];
  float* out = (float*)d_out;
  unsigned char* ws = (unsigned char*)d_ws;   // needs 9,572,352 bytes
  pre_kernel<<<68, 256, 0, stream>>>(q, g, Wq, Wkv, Wo, ws);
  stats_kernel<<<256, 512, 0, stream>>>(c, ws);
  wsum_kernel<<<1024, 256, 0, stream>>>(c, ws);
  gemm_kernel<<<256, 256, 0, stream>>>(bo, ws, out);
}